// Round 1
// baseline (435.957 us; speedup 1.0000x reference)
//
#include <hip/hip_runtime.h>
#include <math.h>

#define DH 128
#define CAP 2048

__device__ __forceinline__ float waveMax(float x) {
    #pragma unroll
    for (int m = 32; m; m >>= 1) x = fmaxf(x, __shfl_xor(x, m));
    return x;
}
__device__ __forceinline__ float waveSum(float x) {
    #pragma unroll
    for (int m = 32; m; m >>= 1) x += __shfl_xor(x, m);
    return x;
}

// K1: h = x@W + b; u = h@a[:128]; v = h@a[128:]. 32 rows per block, W cached in LDS.
__global__ __launch_bounds__(256) void k_matmul(
    const float* __restrict__ x, const float* __restrict__ Wg,
    const float* __restrict__ bg, const float* __restrict__ ag,
    float* __restrict__ h, float* __restrict__ u, float* __restrict__ v, int n)
{
    __shared__ float4 Ws[4096];   // W[k][c] as float4 over c  (64 KB)
    __shared__ float4 Xs[1024];   // 32 rows x 128 cols        (16 KB)
    __shared__ float us[32], vs[32];
    int t = threadIdx.x;
    const float4* W4 = (const float4*)Wg;
    for (int i = t; i < 4096; i += 256) Ws[i] = W4[i];
    int row0 = blockIdx.x * 32;
    const float4* x4 = (const float4*)x;
    for (int i = t; i < 1024; i += 256) {
        int r = i >> 5, c4 = i & 31;
        int gr = row0 + r;
        Xs[i] = (gr < n) ? x4[(size_t)gr * 32 + c4] : float4{0.f, 0.f, 0.f, 0.f};
    }
    __syncthreads();

    int tc = t & 31;   // col group: cols 4*tc..4*tc+3
    int tr = t >> 5;   // row group: rows 4*tr..4*tr+3
    float acc[4][4] = {};
    for (int k4 = 0; k4 < 32; ++k4) {
        float4 wv0 = Ws[(k4 * 4 + 0) * 32 + tc];
        float4 wv1 = Ws[(k4 * 4 + 1) * 32 + tc];
        float4 wv2 = Ws[(k4 * 4 + 2) * 32 + tc];
        float4 wv3 = Ws[(k4 * 4 + 3) * 32 + tc];
        #pragma unroll
        for (int r = 0; r < 4; ++r) {
            float4 xv = Xs[(tr * 4 + r) * 32 + k4];
            acc[r][0] += xv.x * wv0.x + xv.y * wv1.x + xv.z * wv2.x + xv.w * wv3.x;
            acc[r][1] += xv.x * wv0.y + xv.y * wv1.y + xv.z * wv2.y + xv.w * wv3.y;
            acc[r][2] += xv.x * wv0.z + xv.y * wv1.z + xv.z * wv2.z + xv.w * wv3.z;
            acc[r][3] += xv.x * wv0.w + xv.y * wv1.w + xv.z * wv2.w + xv.w * wv3.w;
        }
    }
    float4 bb  = ((const float4*)bg)[tc];
    float4 as_ = ((const float4*)ag)[tc];
    float4 ad_ = ((const float4*)ag)[32 + tc];
    #pragma unroll
    for (int r = 0; r < 4; ++r) {
        int gr = row0 + tr * 4 + r;
        float4 ov;
        ov.x = acc[r][0] + bb.x; ov.y = acc[r][1] + bb.y;
        ov.z = acc[r][2] + bb.z; ov.w = acc[r][3] + bb.w;
        float pu = ov.x * as_.x + ov.y * as_.y + ov.z * as_.z + ov.w * as_.w;
        float pv = ov.x * ad_.x + ov.y * ad_.y + ov.z * ad_.z + ov.w * ad_.w;
        #pragma unroll
        for (int m = 16; m; m >>= 1) { pu += __shfl_xor(pu, m); pv += __shfl_xor(pv, m); }
        if (gr < n) {
            ((float4*)h)[(size_t)gr * 32 + tc] = ov;
            if (tc == 0) { us[tr * 4 + r] = pu; vs[tr * 4 + r] = pv; }
        }
    }
    __syncthreads();
    if (t < 32 && row0 + t < n) { u[row0 + t] = us[t]; v[row0 + t] = vs[t]; }
}

// K2: histogram of src (edges + self loops)
__global__ void k_hist(const int* __restrict__ ei, int E, int n, unsigned* __restrict__ cnt) {
    int e = blockIdx.x * 256 + threadIdx.x;
    if (e < E) atomicAdd(&cnt[ei[e]], 1u);
    else if (e < E + n) atomicAdd(&cnt[e - E], 1u);
}

// K3a: per-block partial sums of cnt
__global__ void k_scan_partial(const unsigned* __restrict__ cnt, unsigned* __restrict__ psum, int n) {
    __shared__ unsigned s[256];
    int t = threadIdx.x, idx = blockIdx.x * 256 + t;
    s[t] = idx < n ? cnt[idx] : 0u;
    __syncthreads();
    for (int d = 128; d; d >>= 1) { if (t < d) s[t] += s[t + d]; __syncthreads(); }
    if (t == 0) psum[blockIdx.x] = s[0];
}

// K3b: exclusive scan of partial sums (B <= 1024)
__global__ void k_scan_top(unsigned* __restrict__ psum, int B) {
    __shared__ unsigned s[1024];
    int t = threadIdx.x;
    unsigned v = t < B ? psum[t] : 0u;
    s[t] = v; __syncthreads();
    for (int d = 1; d < 1024; d <<= 1) {
        unsigned x = (t >= d) ? s[t - d] : 0u;
        __syncthreads();
        s[t] += x;
        __syncthreads();
    }
    if (t < B) psum[t] = s[t] - v;
}

// K3c: local exclusive scan + base → offsets; also init cursor
__global__ void k_scan_final(const unsigned* __restrict__ cnt, const unsigned* __restrict__ psum,
                             unsigned* __restrict__ off, unsigned* __restrict__ cur, int n) {
    __shared__ unsigned s[256];
    int t = threadIdx.x, idx = blockIdx.x * 256 + t;
    unsigned v = idx < n ? cnt[idx] : 0u;
    s[t] = v; __syncthreads();
    for (int d = 1; d < 256; d <<= 1) {
        unsigned x = (t >= d) ? s[t - d] : 0u;
        __syncthreads();
        s[t] += x;
        __syncthreads();
    }
    unsigned excl = s[t] - v + psum[blockIdx.x];
    if (idx < n) {
        off[idx] = excl; cur[idx] = excl;
        if (idx == n - 1) off[n] = excl + v;
    }
}

// K4: scatter dst into CSR order by src
__global__ void k_scatter(const int* __restrict__ ei, int E, int n,
                          unsigned* __restrict__ cur, int* __restrict__ edst) {
    int e = blockIdx.x * 256 + threadIdx.x;
    int s, d;
    if (e < E)          { s = ei[e]; d = ei[E + e]; }
    else if (e < E + n) { s = e - E; d = s; }
    else return;
    unsigned p = atomicAdd(&cur[s], 1u);
    edst[p] = d;
}

// K5: per-node softmax + weighted aggregation + elu. One block (128 thr) per node.
__global__ __launch_bounds__(128) void k_agg(
    const int* __restrict__ edst, const unsigned* __restrict__ off,
    const float* __restrict__ h, const float* __restrict__ u, const float* __restrict__ v,
    const float* __restrict__ ab_p, float* __restrict__ out, int n)
{
    int i = blockIdx.x;
    int t = threadIdx.x;
    unsigned s0 = off[i];
    int deg = (int)(off[i + 1] - s0);
    float ab = ab_p[0];
    float ui = u[i];
    __shared__ float ex_s[CAP];
    __shared__ int   ds_s[CAP];
    __shared__ float red[2];

    // pass 1: logits + max (stash dst & logit in LDS)
    float mx = -1e30f;
    for (int e = t; e < deg; e += 128) {
        int d = edst[s0 + e];
        float lg = ui + v[d] + ab;
        lg = lg >= 0.f ? lg : 0.01f * lg;
        if (e < CAP) { ds_s[e] = d; ex_s[e] = lg; }
        mx = fmaxf(mx, lg);
    }
    mx = waveMax(mx);
    if ((t & 63) == 0) red[t >> 6] = mx;
    __syncthreads();
    mx = fmaxf(red[0], red[1]);
    __syncthreads();

    // pass 2: exp + sum
    float sm = 0.f;
    for (int e = t; e < deg; e += 128) {
        float lg;
        if (e < CAP) lg = ex_s[e];
        else { int d = edst[s0 + e]; lg = ui + v[d] + ab; lg = lg >= 0.f ? lg : 0.01f * lg; }
        float ex = __expf(lg - mx);
        if (e < CAP) ex_s[e] = ex;
        sm += ex;
    }
    sm = waveSum(sm);
    if ((t & 63) == 0) red[t >> 6] = sm;
    __syncthreads();
    float denom = red[0] + red[1];

    // pass 3: out[i][t] = sum_e (ex_e/denom) * h[dst_e][t]
    float o = 0.f;
    for (int e = 0; e < deg; ++e) {
        float w; int d;
        if (e < CAP) { w = ex_s[e]; d = ds_s[e]; }
        else {
            d = edst[s0 + e];
            float lg = ui + v[d] + ab;
            lg = lg >= 0.f ? lg : 0.01f * lg;
            w = __expf(lg - mx);
        }
        o += w * h[(size_t)d * DH + t];
    }
    o /= denom;
    out[(size_t)i * DH + t] = o > 0.f ? o : expm1f(o);
}

extern "C" void kernel_launch(void* const* d_in, const int* in_sizes, int n_in,
                              void* d_out, int out_size, void* d_ws, size_t ws_size,
                              hipStream_t stream) {
    const float* x  = (const float*)d_in[0];
    const int*   ei = (const int*)d_in[1];
    const float* W  = (const float*)d_in[2];
    const float* b  = (const float*)d_in[3];
    const float* a  = (const float*)d_in[4];
    const float* ab = (const float*)d_in[5];
    float* out = (float*)d_out;
    int n  = in_sizes[0] / DH;
    int E  = in_sizes[1] / 2;
    int ET = E + n;

    char* w = (char*)d_ws;
    float*    h    = (float*)w;    w += (size_t)n * DH * 4;
    float*    u    = (float*)w;    w += (size_t)n * 4;
    float*    v    = (float*)w;    w += (size_t)n * 4;
    unsigned* cnt  = (unsigned*)w; w += (size_t)n * 4;
    unsigned* off  = (unsigned*)w; w += (size_t)(n + 1) * 4 + 4;
    unsigned* cur  = (unsigned*)w; w += (size_t)n * 4;
    int*      edst = (int*)w;      w += (size_t)ET * 4;
    unsigned* psum = (unsigned*)w; w += 4096;

    hipMemsetAsync(cnt, 0, (size_t)n * 4, stream);

    int gm = (n + 31) / 32;
    k_matmul<<<gm, 256, 0, stream>>>(x, W, b, a, h, u, v, n);

    int g2 = (ET + 255) / 256;
    k_hist<<<g2, 256, 0, stream>>>(ei, E, n, cnt);

    int B = (n + 255) / 256;
    k_scan_partial<<<B, 256, 0, stream>>>(cnt, psum, n);
    k_scan_top<<<1, 1024, 0, stream>>>(psum, B);
    k_scan_final<<<B, 256, 0, stream>>>(cnt, psum, off, cur, n);

    k_scatter<<<g2, 256, 0, stream>>>(ei, E, n, cur, edst);

    k_agg<<<n, 128, 0, stream>>>(edst, off, h, u, v, ab, out, n);
}

// Round 2
// 392.405 us; speedup vs baseline: 1.1110x; 1.1110x over previous
//
#include <hip/hip_runtime.h>
#include <hip/hip_fp16.h>
#include <math.h>

#define DH 128
#define CAP 256

__device__ __forceinline__ float waveMax(float x) {
    #pragma unroll
    for (int m = 32; m; m >>= 1) x = fmaxf(x, __shfl_xor(x, m));
    return x;
}
__device__ __forceinline__ float waveSum(float x) {
    #pragma unroll
    for (int m = 32; m; m >>= 1) x += __shfl_xor(x, m);
    return x;
}

// K1: h = x@W + b (stored fp16); u = h@a[:128]; v = h@a[128:]; plus fused src-histogram.
__global__ __launch_bounds__(256) void k_matmul(
    const float* __restrict__ x, const float* __restrict__ Wg,
    const float* __restrict__ bg, const float* __restrict__ ag,
    __half2* __restrict__ h2, float* __restrict__ u, float* __restrict__ v, int n,
    const int* __restrict__ ei, int E, unsigned* __restrict__ cnt)
{
    __shared__ float4 Ws[4096];   // W[k][c] as float4 over c  (64 KB)
    __shared__ float4 Xs[1024];   // 32 rows x 128 cols        (16 KB)
    __shared__ float us[32], vs[32];
    int t = threadIdx.x;
    const float4* W4 = (const float4*)Wg;
    for (int i = t; i < 4096; i += 256) Ws[i] = W4[i];
    int row0 = blockIdx.x * 32;
    const float4* x4 = (const float4*)x;
    for (int i = t; i < 1024; i += 256) {
        int r = i >> 5, c4 = i & 31;
        int gr = row0 + r;
        Xs[i] = (gr < n) ? x4[(size_t)gr * 32 + c4] : float4{0.f, 0.f, 0.f, 0.f};
    }
    __syncthreads();

    int tc = t & 31;   // col group: cols 4*tc..4*tc+3
    int tr = t >> 5;   // row group: rows 4*tr..4*tr+3
    float acc[4][4] = {};
    for (int k4 = 0; k4 < 32; ++k4) {
        float4 wv0 = Ws[(k4 * 4 + 0) * 32 + tc];
        float4 wv1 = Ws[(k4 * 4 + 1) * 32 + tc];
        float4 wv2 = Ws[(k4 * 4 + 2) * 32 + tc];
        float4 wv3 = Ws[(k4 * 4 + 3) * 32 + tc];
        #pragma unroll
        for (int r = 0; r < 4; ++r) {
            float4 xv = Xs[(tr * 4 + r) * 32 + k4];
            acc[r][0] += xv.x * wv0.x + xv.y * wv1.x + xv.z * wv2.x + xv.w * wv3.x;
            acc[r][1] += xv.x * wv0.y + xv.y * wv1.y + xv.z * wv2.y + xv.w * wv3.y;
            acc[r][2] += xv.x * wv0.z + xv.y * wv1.z + xv.z * wv2.z + xv.w * wv3.z;
            acc[r][3] += xv.x * wv0.w + xv.y * wv1.w + xv.z * wv2.w + xv.w * wv3.w;
        }
    }
    float4 bb  = ((const float4*)bg)[tc];
    float4 as_ = ((const float4*)ag)[tc];
    float4 ad_ = ((const float4*)ag)[32 + tc];
    #pragma unroll
    for (int r = 0; r < 4; ++r) {
        int gr = row0 + tr * 4 + r;
        float4 ov;
        ov.x = acc[r][0] + bb.x; ov.y = acc[r][1] + bb.y;
        ov.z = acc[r][2] + bb.z; ov.w = acc[r][3] + bb.w;
        float pu = ov.x * as_.x + ov.y * as_.y + ov.z * as_.z + ov.w * as_.w;
        float pv = ov.x * ad_.x + ov.y * ad_.y + ov.z * ad_.z + ov.w * ad_.w;
        #pragma unroll
        for (int m = 16; m; m >>= 1) { pu += __shfl_xor(pu, m); pv += __shfl_xor(pv, m); }
        if (gr < n) {
            __half2* hrow = h2 + (size_t)gr * 64;
            hrow[tc * 2]     = __floats2half2_rn(ov.x, ov.y);
            hrow[tc * 2 + 1] = __floats2half2_rn(ov.z, ov.w);
            if (tc == 0) { us[tr * 4 + r] = pu; vs[tr * 4 + r] = pv; }
        }
    }
    __syncthreads();
    if (t < 32 && row0 + t < n) { u[row0 + t] = us[t]; v[row0 + t] = vs[t]; }

    // fused histogram of src (edges + self-loops), grid-stride
    int gsz = gridDim.x * 256;
    for (int e = blockIdx.x * 256 + t; e < E + n; e += gsz) {
        if (e < E) atomicAdd(&cnt[ei[e]], 1u);
        else       atomicAdd(&cnt[e - E], 1u);
    }
}

// K3a: per-block partial sums of cnt
__global__ void k_scan_partial(const unsigned* __restrict__ cnt, unsigned* __restrict__ psum, int n) {
    __shared__ unsigned s[256];
    int t = threadIdx.x, idx = blockIdx.x * 256 + t;
    s[t] = idx < n ? cnt[idx] : 0u;
    __syncthreads();
    for (int d = 128; d; d >>= 1) { if (t < d) s[t] += s[t + d]; __syncthreads(); }
    if (t == 0) psum[blockIdx.x] = s[0];
}

// K3b: exclusive scan of partial sums (B <= 1024)
__global__ void k_scan_top(unsigned* __restrict__ psum, int B) {
    __shared__ unsigned s[1024];
    int t = threadIdx.x;
    unsigned v = t < B ? psum[t] : 0u;
    s[t] = v; __syncthreads();
    for (int d = 1; d < 1024; d <<= 1) {
        unsigned x = (t >= d) ? s[t - d] : 0u;
        __syncthreads();
        s[t] += x;
        __syncthreads();
    }
    if (t < B) psum[t] = s[t] - v;
}

// K3c: local exclusive scan + base → offsets; also init cursor
__global__ void k_scan_final(const unsigned* __restrict__ cnt, const unsigned* __restrict__ psum,
                             unsigned* __restrict__ off, unsigned* __restrict__ cur, int n) {
    __shared__ unsigned s[256];
    int t = threadIdx.x, idx = blockIdx.x * 256 + t;
    unsigned v = idx < n ? cnt[idx] : 0u;
    s[t] = v; __syncthreads();
    for (int d = 1; d < 256; d <<= 1) {
        unsigned x = (t >= d) ? s[t - d] : 0u;
        __syncthreads();
        s[t] += x;
        __syncthreads();
    }
    unsigned excl = s[t] - v + psum[blockIdx.x];
    if (idx < n) {
        off[idx] = excl; cur[idx] = excl;
        if (idx == n - 1) off[n] = excl + v;
    }
}

// K4: scatter dst into CSR order by src
__global__ void k_scatter(const int* __restrict__ ei, int E, int n,
                          unsigned* __restrict__ cur, int* __restrict__ edst) {
    int e = blockIdx.x * 256 + threadIdx.x;
    int s, d;
    if (e < E)          { s = ei[e]; d = ei[E + e]; }
    else if (e < E + n) { s = e - E; d = s; }
    else return;
    unsigned p = atomicAdd(&cur[s], 1u);
    edst[p] = d;
}

// K5: per-node softmax + weighted fp16 aggregation + elu. 256 threads (4 waves) per node.
__global__ __launch_bounds__(256) void k_agg(
    const int* __restrict__ edst, const unsigned* __restrict__ off,
    const __half2* __restrict__ h2, const float* __restrict__ u, const float* __restrict__ v,
    const float* __restrict__ ab_p, float* __restrict__ out, int n)
{
    int i = blockIdx.x;
    int t = threadIdx.x;
    int wave = t >> 6, lane = t & 63;
    unsigned s0 = off[i];
    int deg = (int)(off[i + 1] - s0);
    float ab = ab_p[0];
    float ui = u[i];
    __shared__ float ex_s[CAP];
    __shared__ int   ds_s[CAP];
    __shared__ float red[4];
    __shared__ float2 part[4][64];

    // pass 1: logits + max (stash dst & logit in LDS)
    float mx = -1e30f;
    for (int e = t; e < deg; e += 256) {
        int d = edst[s0 + e];
        float lg = ui + v[d] + ab;
        lg = lg >= 0.f ? lg : 0.01f * lg;
        if (e < CAP) { ds_s[e] = d; ex_s[e] = lg; }
        mx = fmaxf(mx, lg);
    }
    mx = waveMax(mx);
    if (lane == 0) red[wave] = mx;
    __syncthreads();
    mx = fmaxf(fmaxf(red[0], red[1]), fmaxf(red[2], red[3]));
    __syncthreads();

    // pass 2: exp + sum
    float sm = 0.f;
    for (int e = t; e < deg; e += 256) {
        float lg;
        if (e < CAP) lg = ex_s[e];
        else { int d = edst[s0 + e]; lg = ui + v[d] + ab; lg = lg >= 0.f ? lg : 0.01f * lg; }
        float ex = __expf(lg - mx);
        if (e < CAP) ex_s[e] = ex;
        sm += ex;
    }
    sm = waveSum(sm);
    if (lane == 0) red[wave] = sm;
    __syncthreads();
    float denom = red[0] + red[1] + red[2] + red[3];

    // pass 3: each wave owns one edge per iteration; lane l covers cols 2l, 2l+1
    float2 acc = {0.f, 0.f};
    for (int e = wave; e < deg; e += 4) {
        float w; int d;
        if (e < CAP) { w = ex_s[e]; d = ds_s[e]; }
        else {
            d = edst[s0 + e];
            float lg = ui + v[d] + ab;
            lg = lg >= 0.f ? lg : 0.01f * lg;
            w = __expf(lg - mx);
        }
        __half2 hv = h2[(size_t)d * 64 + lane];
        float2 hf = __half22float2(hv);
        acc.x += w * hf.x;
        acc.y += w * hf.y;
    }
    part[wave][lane] = acc;
    __syncthreads();
    if (t < 64) {
        float2 o;
        o.x = part[0][t].x + part[1][t].x + part[2][t].x + part[3][t].x;
        o.y = part[0][t].y + part[1][t].y + part[2][t].y + part[3][t].y;
        o.x /= denom; o.y /= denom;
        o.x = o.x > 0.f ? o.x : expm1f(o.x);
        o.y = o.y > 0.f ? o.y : expm1f(o.y);
        ((float2*)out)[(size_t)i * 64 + t] = o;
    }
}

extern "C" void kernel_launch(void* const* d_in, const int* in_sizes, int n_in,
                              void* d_out, int out_size, void* d_ws, size_t ws_size,
                              hipStream_t stream) {
    const float* x  = (const float*)d_in[0];
    const int*   ei = (const int*)d_in[1];
    const float* W  = (const float*)d_in[2];
    const float* b  = (const float*)d_in[3];
    const float* a  = (const float*)d_in[4];
    const float* ab = (const float*)d_in[5];
    float* out = (float*)d_out;
    int n  = in_sizes[0] / DH;
    int E  = in_sizes[1] / 2;
    int ET = E + n;

    char* w = (char*)d_ws;
    __half2*  h2   = (__half2*)w;  w += (size_t)n * DH * 2;
    float*    u    = (float*)w;    w += (size_t)n * 4;
    float*    v    = (float*)w;    w += (size_t)n * 4;
    unsigned* cnt  = (unsigned*)w; w += (size_t)n * 4;
    unsigned* off  = (unsigned*)w; w += (size_t)(n + 1) * 4 + 4;
    unsigned* cur  = (unsigned*)w; w += (size_t)n * 4;
    int*      edst = (int*)w;      w += (size_t)ET * 4;
    unsigned* psum = (unsigned*)w; w += 4096;

    hipMemsetAsync(cnt, 0, (size_t)n * 4, stream);

    int gm = (n + 31) / 32;
    k_matmul<<<gm, 256, 0, stream>>>(x, W, b, a, h2, u, v, n, ei, E, cnt);

    int B = (n + 255) / 256;
    k_scan_partial<<<B, 256, 0, stream>>>(cnt, psum, n);
    k_scan_top<<<1, 1024, 0, stream>>>(psum, B);
    k_scan_final<<<B, 256, 0, stream>>>(cnt, psum, off, cur, n);

    int g2 = (ET + 255) / 256;
    k_scatter<<<g2, 256, 0, stream>>>(ei, E, n, cur, edst);

    k_agg<<<n, 256, 0, stream>>>(edst, off, h2, u, v, ab, out, n);
}

// Round 3
// 309.423 us; speedup vs baseline: 1.4089x; 1.2682x over previous
//
#include <hip/hip_runtime.h>
#include <hip/hip_fp16.h>
#include <math.h>

#define DH 128
#define CAPW 128

__device__ __forceinline__ float waveMax(float x) {
    #pragma unroll
    for (int m = 32; m; m >>= 1) x = fmaxf(x, __shfl_xor(x, m));
    return x;
}
__device__ __forceinline__ float waveSum(float x) {
    #pragma unroll
    for (int m = 32; m; m >>= 1) x += __shfl_xor(x, m);
    return x;
}
__device__ __forceinline__ unsigned waveSumU(unsigned x) {
    #pragma unroll
    for (int m = 32; m; m >>= 1) x += __shfl_xor(x, m);
    return x;
}

// K1: h = x@W + b (stored fp16); u = h@a[:128]; v = h@a[128:]; plus fused src-histogram.
__global__ __launch_bounds__(256) void k_matmul(
    const float* __restrict__ x, const float* __restrict__ Wg,
    const float* __restrict__ bg, const float* __restrict__ ag,
    __half2* __restrict__ h2, float* __restrict__ u, float* __restrict__ v, int n,
    const int* __restrict__ ei, int E, unsigned* __restrict__ cnt)
{
    __shared__ float4 Ws[4096];   // W[k][c] as float4 over c  (64 KB)
    __shared__ float4 Xs[1024];   // 32 rows x 128 cols        (16 KB)
    __shared__ float us[32], vs[32];
    int t = threadIdx.x;
    const float4* W4 = (const float4*)Wg;
    for (int i = t; i < 4096; i += 256) Ws[i] = W4[i];
    int row0 = blockIdx.x * 32;
    const float4* x4 = (const float4*)x;
    for (int i = t; i < 1024; i += 256) {
        int r = i >> 5, c4 = i & 31;
        int gr = row0 + r;
        Xs[i] = (gr < n) ? x4[(size_t)gr * 32 + c4] : float4{0.f, 0.f, 0.f, 0.f};
    }
    __syncthreads();

    int tc = t & 31;   // col group: cols 4*tc..4*tc+3
    int tr = t >> 5;   // row group: rows 4*tr..4*tr+3
    float acc[4][4] = {};
    for (int k4 = 0; k4 < 32; ++k4) {
        float4 wv0 = Ws[(k4 * 4 + 0) * 32 + tc];
        float4 wv1 = Ws[(k4 * 4 + 1) * 32 + tc];
        float4 wv2 = Ws[(k4 * 4 + 2) * 32 + tc];
        float4 wv3 = Ws[(k4 * 4 + 3) * 32 + tc];
        #pragma unroll
        for (int r = 0; r < 4; ++r) {
            float4 xv = Xs[(tr * 4 + r) * 32 + k4];
            acc[r][0] += xv.x * wv0.x + xv.y * wv1.x + xv.z * wv2.x + xv.w * wv3.x;
            acc[r][1] += xv.x * wv0.y + xv.y * wv1.y + xv.z * wv2.y + xv.w * wv3.y;
            acc[r][2] += xv.x * wv0.z + xv.y * wv1.z + xv.z * wv2.z + xv.w * wv3.z;
            acc[r][3] += xv.x * wv0.w + xv.y * wv1.w + xv.z * wv2.w + xv.w * wv3.w;
        }
    }
    float4 bb  = ((const float4*)bg)[tc];
    float4 as_ = ((const float4*)ag)[tc];
    float4 ad_ = ((const float4*)ag)[32 + tc];
    #pragma unroll
    for (int r = 0; r < 4; ++r) {
        int gr = row0 + tr * 4 + r;
        float4 ov;
        ov.x = acc[r][0] + bb.x; ov.y = acc[r][1] + bb.y;
        ov.z = acc[r][2] + bb.z; ov.w = acc[r][3] + bb.w;
        float pu = ov.x * as_.x + ov.y * as_.y + ov.z * as_.z + ov.w * as_.w;
        float pv = ov.x * ad_.x + ov.y * ad_.y + ov.z * ad_.z + ov.w * ad_.w;
        #pragma unroll
        for (int m = 16; m; m >>= 1) { pu += __shfl_xor(pu, m); pv += __shfl_xor(pv, m); }
        if (gr < n) {
            __half2* hrow = h2 + (size_t)gr * 64;
            hrow[tc * 2]     = __floats2half2_rn(ov.x, ov.y);
            hrow[tc * 2 + 1] = __floats2half2_rn(ov.z, ov.w);
            if (tc == 0) { us[tr * 4 + r] = pu; vs[tr * 4 + r] = pv; }
        }
    }
    __syncthreads();
    if (t < 32 && row0 + t < n) { u[row0 + t] = us[t]; v[row0 + t] = vs[t]; }

    // fused histogram of src (edges + self-loops), grid-stride
    int gsz = gridDim.x * 256;
    for (int e = blockIdx.x * 256 + t; e < E + n; e += gsz) {
        if (e < E) atomicAdd(&cnt[ei[e]], 1u);
        else       atomicAdd(&cnt[e - E], 1u);
    }
}

// K2: per-block partial sums of cnt
__global__ void k_scan_partial(const unsigned* __restrict__ cnt, unsigned* __restrict__ psum, int n) {
    __shared__ unsigned s[256];
    int t = threadIdx.x, idx = blockIdx.x * 256 + t;
    s[t] = idx < n ? cnt[idx] : 0u;
    __syncthreads();
    for (int d = 128; d; d >>= 1) { if (t < d) s[t] += s[t + d]; __syncthreads(); }
    if (t == 0) psum[blockIdx.x] = s[0];
}

// K3: local exclusive scan; base computed in-kernel by reducing psum[0..bid-1] (B<=256)
__global__ void k_scan_final(const unsigned* __restrict__ cnt, const unsigned* __restrict__ psum,
                             unsigned* __restrict__ off, unsigned* __restrict__ cur, int n) {
    __shared__ unsigned s[256];
    __shared__ unsigned wred[4];
    int t = threadIdx.x, idx = blockIdx.x * 256 + t;
    // base = sum of psum[j] for j < blockIdx.x  (B <= 256)
    unsigned p = (t < blockIdx.x) ? psum[t] : 0u;
    p = waveSumU(p);
    if ((t & 63) == 0) wred[t >> 6] = p;
    __syncthreads();
    unsigned base = wred[0] + wred[1] + wred[2] + wred[3];

    unsigned v = idx < n ? cnt[idx] : 0u;
    s[t] = v; __syncthreads();
    for (int d = 1; d < 256; d <<= 1) {
        unsigned x = (t >= d) ? s[t - d] : 0u;
        __syncthreads();
        s[t] += x;
        __syncthreads();
    }
    unsigned excl = s[t] - v + base;
    if (idx < n) {
        off[idx] = excl; cur[idx] = excl;
        if (idx == n - 1) off[n] = excl + v;
    }
}

// K4: scatter dst into CSR order by src
__global__ void k_scatter(const int* __restrict__ ei, int E, int n,
                          unsigned* __restrict__ cur, int* __restrict__ edst) {
    int e = blockIdx.x * 256 + threadIdx.x;
    int s, d;
    if (e < E)          { s = ei[e]; d = ei[E + e]; }
    else if (e < E + n) { s = e - E; d = s; }
    else return;
    unsigned p = atomicAdd(&cur[s], 1u);
    edst[p] = d;
}

// K5: one WAVE per node, 4 nodes per block. Barrier-free (wave-synchronous LDS).
// Pass 3: four 16-lane groups, each loads a full 256B h-row as dwordx4.
__global__ __launch_bounds__(256) void k_agg(
    const int* __restrict__ edst, const unsigned* __restrict__ off,
    const __half2* __restrict__ h2, const float* __restrict__ u, const float* __restrict__ v,
    const float* __restrict__ ab_p, float* __restrict__ out, int n)
{
    __shared__ float ex_s[4][CAPW];
    __shared__ int   ds_s[4][CAPW];
    int t = threadIdx.x;
    int wave = t >> 6, lane = t & 63;
    int i = blockIdx.x * 4 + wave;
    if (i >= n) return;
    unsigned s0 = off[i];
    int deg = (int)(off[i + 1] - s0);
    float ab = ab_p[0];
    float ui = u[i];

    // pass 1: logits + wave max (stash dst & logit)
    float mx = -1e30f;
    for (int e = lane; e < deg; e += 64) {
        int d = edst[s0 + e];
        float lg = ui + v[d] + ab;
        lg = lg >= 0.f ? lg : 0.01f * lg;
        if (e < CAPW) { ds_s[wave][e] = d; ex_s[wave][e] = lg; }
        mx = fmaxf(mx, lg);
    }
    mx = waveMax(mx);

    // pass 2: exp + wave sum
    float sm = 0.f;
    for (int e = lane; e < deg; e += 64) {
        float lg;
        if (e < CAPW) lg = ex_s[wave][e];
        else { int d = edst[s0 + e]; lg = ui + v[d] + ab; lg = lg >= 0.f ? lg : 0.01f * lg; }
        float ex = __expf(lg - mx);
        if (e < CAPW) ex_s[wave][e] = ex;
        sm += ex;
    }
    sm = waveSum(sm);
    float inv = 1.f / sm;

    // pass 3: group g (lanes 16g..16g+15) handles edges g, g+4, ...
    // lane gl loads 8 halves (float4) covering cols 8gl..8gl+7
    int g = lane >> 4, gl = lane & 15;
    float acc[8] = {};
    for (int e = g; e < deg; e += 4) {
        float w; int d;
        if (e < CAPW) { w = ex_s[wave][e]; d = ds_s[wave][e]; }
        else {
            d = edst[s0 + e];
            float lg = ui + v[d] + ab;
            lg = lg >= 0.f ? lg : 0.01f * lg;
            w = __expf(lg - mx);
        }
        float4 raw = ((const float4*)(h2 + (size_t)d * 64))[gl];
        const __half2* hp = (const __half2*)&raw;
        float2 f0 = __half22float2(hp[0]), f1 = __half22float2(hp[1]);
        float2 f2 = __half22float2(hp[2]), f3 = __half22float2(hp[3]);
        acc[0] += w * f0.x; acc[1] += w * f0.y;
        acc[2] += w * f1.x; acc[3] += w * f1.y;
        acc[4] += w * f2.x; acc[5] += w * f2.y;
        acc[6] += w * f3.x; acc[7] += w * f3.y;
    }
    // reduce the 4 groups (lanes sharing gl)
    #pragma unroll
    for (int k = 0; k < 8; ++k) {
        acc[k] += __shfl_xor(acc[k], 16);
        acc[k] += __shfl_xor(acc[k], 32);
    }
    if (g == 0) {
        float o[8];
        #pragma unroll
        for (int k = 0; k < 8; ++k) {
            float z = acc[k] * inv;
            o[k] = z > 0.f ? z : expm1f(z);
        }
        float4* orow = (float4*)(out + (size_t)i * DH);
        orow[gl * 2]     = float4{o[0], o[1], o[2], o[3]};
        orow[gl * 2 + 1] = float4{o[4], o[5], o[6], o[7]};
    }
}

extern "C" void kernel_launch(void* const* d_in, const int* in_sizes, int n_in,
                              void* d_out, int out_size, void* d_ws, size_t ws_size,
                              hipStream_t stream) {
    const float* x  = (const float*)d_in[0];
    const int*   ei = (const int*)d_in[1];
    const float* W  = (const float*)d_in[2];
    const float* b  = (const float*)d_in[3];
    const float* a  = (const float*)d_in[4];
    const float* ab = (const float*)d_in[5];
    float* out = (float*)d_out;
    int n  = in_sizes[0] / DH;
    int E  = in_sizes[1] / 2;
    int ET = E + n;

    char* w = (char*)d_ws;
    __half2*  h2   = (__half2*)w;  w += (size_t)n * DH * 2;
    float*    u    = (float*)w;    w += (size_t)n * 4;
    float*    v    = (float*)w;    w += (size_t)n * 4;
    unsigned* cnt  = (unsigned*)w; w += (size_t)n * 4;
    unsigned* off  = (unsigned*)w; w += (size_t)(n + 1) * 4 + 4;
    unsigned* cur  = (unsigned*)w; w += (size_t)n * 4;
    int*      edst = (int*)w;      w += (size_t)ET * 4;
    unsigned* psum = (unsigned*)w; w += 4096;

    hipMemsetAsync(cnt, 0, (size_t)n * 4, stream);

    int gm = (n + 31) / 32;
    k_matmul<<<gm, 256, 0, stream>>>(x, W, b, a, h2, u, v, n, ei, E, cnt);

    int B = (n + 255) / 256;
    k_scan_partial<<<B, 256, 0, stream>>>(cnt, psum, n);
    k_scan_final<<<B, 256, 0, stream>>>(cnt, psum, off, cur, n);

    int g2 = (ET + 255) / 256;
    k_scatter<<<g2, 256, 0, stream>>>(ei, E, n, cur, edst);

    k_agg<<<(n + 3) / 4, 256, 0, stream>>>(edst, off, h2, u, v, ab, out, n);
}

// Round 5
// 264.608 us; speedup vs baseline: 1.6476x; 1.1694x over previous
//
#include <hip/hip_runtime.h>
#include <hip/hip_fp16.h>
#include <math.h>

#define DH 128
#define CAPW 128

__device__ __forceinline__ float waveMax(float x) {
    #pragma unroll
    for (int m = 32; m; m >>= 1) x = fmaxf(x, __shfl_xor(x, m));
    return x;
}
__device__ __forceinline__ float waveSum(float x) {
    #pragma unroll
    for (int m = 32; m; m >>= 1) x += __shfl_xor(x, m);
    return x;
}
__device__ __forceinline__ unsigned waveSumU(unsigned x) {
    #pragma unroll
    for (int m = 32; m; m >>= 1) x += __shfl_xor(x, m);
    return x;
}

// K1: h = x@W + b (stored fp16); u = h@a[:128]; v = h@a[128:]; plus fused src-histogram.
__global__ __launch_bounds__(256) void k_matmul(
    const float* __restrict__ x, const float* __restrict__ Wg,
    const float* __restrict__ bg, const float* __restrict__ ag,
    __half2* __restrict__ h2, float* __restrict__ u, float* __restrict__ v, int n,
    const int* __restrict__ ei, int E, unsigned* __restrict__ cnt)
{
    __shared__ float4 Ws[4096];   // W[k][c] as float4 over c  (64 KB)
    __shared__ float4 Xs[1024];   // 32 rows x 128 cols        (16 KB)
    __shared__ float us[32], vs[32];
    int t = threadIdx.x;
    const float4* W4 = (const float4*)Wg;
    for (int i = t; i < 4096; i += 256) Ws[i] = W4[i];
    int row0 = blockIdx.x * 32;
    const float4* x4 = (const float4*)x;
    for (int i = t; i < 1024; i += 256) {
        int r = i >> 5, c4 = i & 31;
        int gr = row0 + r;
        Xs[i] = (gr < n) ? x4[(size_t)gr * 32 + c4] : float4{0.f, 0.f, 0.f, 0.f};
    }
    __syncthreads();

    int tc = t & 31;   // col group: cols 4*tc..4*tc+3
    int tr = t >> 5;   // row group: rows 4*tr..4*tr+3
    float acc[4][4] = {};
    for (int k4 = 0; k4 < 32; ++k4) {
        float4 wv0 = Ws[(k4 * 4 + 0) * 32 + tc];
        float4 wv1 = Ws[(k4 * 4 + 1) * 32 + tc];
        float4 wv2 = Ws[(k4 * 4 + 2) * 32 + tc];
        float4 wv3 = Ws[(k4 * 4 + 3) * 32 + tc];
        #pragma unroll
        for (int r = 0; r < 4; ++r) {
            float4 xv = Xs[(tr * 4 + r) * 32 + k4];
            acc[r][0] += xv.x * wv0.x + xv.y * wv1.x + xv.z * wv2.x + xv.w * wv3.x;
            acc[r][1] += xv.x * wv0.y + xv.y * wv1.y + xv.z * wv2.y + xv.w * wv3.y;
            acc[r][2] += xv.x * wv0.z + xv.y * wv1.z + xv.z * wv2.z + xv.w * wv3.z;
            acc[r][3] += xv.x * wv0.w + xv.y * wv1.w + xv.z * wv2.w + xv.w * wv3.w;
        }
    }
    float4 bb  = ((const float4*)bg)[tc];
    float4 as_ = ((const float4*)ag)[tc];
    float4 ad_ = ((const float4*)ag)[32 + tc];
    #pragma unroll
    for (int r = 0; r < 4; ++r) {
        int gr = row0 + tr * 4 + r;
        float4 ov;
        ov.x = acc[r][0] + bb.x; ov.y = acc[r][1] + bb.y;
        ov.z = acc[r][2] + bb.z; ov.w = acc[r][3] + bb.w;
        float pu = ov.x * as_.x + ov.y * as_.y + ov.z * as_.z + ov.w * as_.w;
        float pv = ov.x * ad_.x + ov.y * ad_.y + ov.z * ad_.z + ov.w * ad_.w;
        #pragma unroll
        for (int m = 16; m; m >>= 1) { pu += __shfl_xor(pu, m); pv += __shfl_xor(pv, m); }
        if (gr < n) {
            __half2* hrow = h2 + (size_t)gr * 64;
            hrow[tc * 2]     = __floats2half2_rn(ov.x, ov.y);
            hrow[tc * 2 + 1] = __floats2half2_rn(ov.z, ov.w);
            if (tc == 0) { us[tr * 4 + r] = pu; vs[tr * 4 + r] = pv; }
        }
    }
    __syncthreads();
    if (t < 32 && row0 + t < n) { u[row0 + t] = us[t]; v[row0 + t] = vs[t]; }

    // fused histogram of src (edges + self-loops), grid-stride
    int gsz = gridDim.x * 256;
    for (int e = blockIdx.x * 256 + t; e < E + n; e += gsz) {
        if (e < E) atomicAdd(&cnt[ei[e]], 1u);
        else       atomicAdd(&cnt[e - E], 1u);
    }
}

// K2: per-block partial sums of cnt
__global__ void k_scan_partial(const unsigned* __restrict__ cnt, unsigned* __restrict__ psum, int n) {
    __shared__ unsigned s[256];
    int t = threadIdx.x, idx = blockIdx.x * 256 + t;
    s[t] = idx < n ? cnt[idx] : 0u;
    __syncthreads();
    for (int d = 128; d; d >>= 1) { if (t < d) s[t] += s[t + d]; __syncthreads(); }
    if (t == 0) psum[blockIdx.x] = s[0];
}

// K3: local exclusive scan; base computed in-kernel by reducing psum[0..bid-1] (B<=256)
__global__ void k_scan_final(const unsigned* __restrict__ cnt, const unsigned* __restrict__ psum,
                             unsigned* __restrict__ off, unsigned* __restrict__ cur, int n) {
    __shared__ unsigned s[256];
    __shared__ unsigned wred[4];
    int t = threadIdx.x, idx = blockIdx.x * 256 + t;
    unsigned p = (t < blockIdx.x) ? psum[t] : 0u;
    p = waveSumU(p);
    if ((t & 63) == 0) wred[t >> 6] = p;
    __syncthreads();
    unsigned base = wred[0] + wred[1] + wred[2] + wred[3];

    unsigned v = idx < n ? cnt[idx] : 0u;
    s[t] = v; __syncthreads();
    for (int d = 1; d < 256; d <<= 1) {
        unsigned x = (t >= d) ? s[t - d] : 0u;
        __syncthreads();
        s[t] += x;
        __syncthreads();
    }
    unsigned excl = s[t] - v + base;
    if (idx < n) {
        off[idx] = excl; cur[idx] = excl;
        if (idx == n - 1) off[n] = excl + v;
    }
}

// K4: XCD-partitioned scatter. Group g = blockIdx&7 handles src in [g*n/8,(g+1)*n/8).
// GRID MUST BE A MULTIPLE OF 8 (launched with 2048 blocks = 8 groups x 256):
// remainder blocks would alias group 0's edge coverage and double-scatter (round-4 bug).
// With round-robin block->XCD dispatch each edst line is written by one XCD only,
// and the group's ~825KB target region stays resident in that XCD's 4MB L2.
// Correct regardless of actual XCD mapping (each edge processed exactly once).
__global__ __launch_bounds__(256) void k_scatter(
    const int* __restrict__ ei, int E, int n,
    unsigned* __restrict__ cur, int* __restrict__ edst)
{
    int grp  = blockIdx.x & 7;
    int gid  = blockIdx.x >> 3;
    int ngrp = gridDim.x >> 3;
    int lo = (int)((long long)grp * n >> 3);
    int hi = (int)((long long)(grp + 1) * n >> 3);
    int ET = E + n;
    int stride = ngrp * 256;
    for (int e = gid * 256 + threadIdx.x; e < ET; e += stride) {
        int s, d;
        if (e < E) { s = ei[e]; d = ei[E + e]; }
        else       { s = e - E; d = s; }
        if (s >= lo && s < hi) {
            unsigned p = atomicAdd(&cur[s], 1u);
            edst[p] = d;
        }
    }
}

// K5: one WAVE per node, 4 nodes per block. Barrier-free (wave-synchronous LDS).
__global__ __launch_bounds__(256) void k_agg(
    const int* __restrict__ edst, const unsigned* __restrict__ off,
    const __half2* __restrict__ h2, const float* __restrict__ u, const float* __restrict__ v,
    const float* __restrict__ ab_p, float* __restrict__ out, int n)
{
    __shared__ float ex_s[4][CAPW];
    __shared__ int   ds_s[4][CAPW];
    int t = threadIdx.x;
    int wave = t >> 6, lane = t & 63;
    int i = blockIdx.x * 4 + wave;
    if (i >= n) return;
    unsigned s0 = off[i];
    int deg = (int)(off[i + 1] - s0);
    float ab = ab_p[0];
    float ui = u[i];

    // pass 1: logits + wave max (stash dst & logit)
    float mx = -1e30f;
    for (int e = lane; e < deg; e += 64) {
        int d = edst[s0 + e];
        float lg = ui + v[d] + ab;
        lg = lg >= 0.f ? lg : 0.01f * lg;
        if (e < CAPW) { ds_s[wave][e] = d; ex_s[wave][e] = lg; }
        mx = fmaxf(mx, lg);
    }
    mx = waveMax(mx);

    // pass 2: exp + wave sum
    float sm = 0.f;
    for (int e = lane; e < deg; e += 64) {
        float lg;
        if (e < CAPW) lg = ex_s[wave][e];
        else { int d = edst[s0 + e]; lg = ui + v[d] + ab; lg = lg >= 0.f ? lg : 0.01f * lg; }
        float ex = __expf(lg - mx);
        if (e < CAPW) ex_s[wave][e] = ex;
        sm += ex;
    }
    sm = waveSum(sm);
    float inv = 1.f / sm;

    // pass 3: group g (lanes 16g..16g+15) handles edges g, g+4, ...
    int g = lane >> 4, gl = lane & 15;
    float acc[8] = {};
    for (int e = g; e < deg; e += 4) {
        float w; int d;
        if (e < CAPW) { w = ex_s[wave][e]; d = ds_s[wave][e]; }
        else {
            d = edst[s0 + e];
            float lg = ui + v[d] + ab;
            lg = lg >= 0.f ? lg : 0.01f * lg;
            w = __expf(lg - mx);
        }
        float4 raw = ((const float4*)(h2 + (size_t)d * 64))[gl];
        const __half2* hp = (const __half2*)&raw;
        float2 f0 = __half22float2(hp[0]), f1 = __half22float2(hp[1]);
        float2 f2 = __half22float2(hp[2]), f3 = __half22float2(hp[3]);
        acc[0] += w * f0.x; acc[1] += w * f0.y;
        acc[2] += w * f1.x; acc[3] += w * f1.y;
        acc[4] += w * f2.x; acc[5] += w * f2.y;
        acc[6] += w * f3.x; acc[7] += w * f3.y;
    }
    #pragma unroll
    for (int k = 0; k < 8; ++k) {
        acc[k] += __shfl_xor(acc[k], 16);
        acc[k] += __shfl_xor(acc[k], 32);
    }
    if (g == 0) {
        float o[8];
        #pragma unroll
        for (int k = 0; k < 8; ++k) {
            float z = acc[k] * inv;
            o[k] = z > 0.f ? z : expm1f(z);
        }
        float4* orow = (float4*)(out + (size_t)i * DH);
        orow[gl * 2]     = float4{o[0], o[1], o[2], o[3]};
        orow[gl * 2 + 1] = float4{o[4], o[5], o[6], o[7]};
    }
}

extern "C" void kernel_launch(void* const* d_in, const int* in_sizes, int n_in,
                              void* d_out, int out_size, void* d_ws, size_t ws_size,
                              hipStream_t stream) {
    const float* x  = (const float*)d_in[0];
    const int*   ei = (const int*)d_in[1];
    const float* W  = (const float*)d_in[2];
    const float* b  = (const float*)d_in[3];
    const float* a  = (const float*)d_in[4];
    const float* ab = (const float*)d_in[5];
    float* out = (float*)d_out;
    int n  = in_sizes[0] / DH;
    int E  = in_sizes[1] / 2;
    int ET = E + n;

    char* w = (char*)d_ws;
    __half2*  h2   = (__half2*)w;  w += (size_t)n * DH * 2;
    float*    u    = (float*)w;    w += (size_t)n * 4;
    float*    v    = (float*)w;    w += (size_t)n * 4;
    unsigned* cnt  = (unsigned*)w; w += (size_t)n * 4;
    unsigned* off  = (unsigned*)w; w += (size_t)(n + 1) * 4 + 4;
    unsigned* cur  = (unsigned*)w; w += (size_t)n * 4;
    int*      edst = (int*)w;      w += (size_t)ET * 4;
    unsigned* psum = (unsigned*)w; w += 4096;

    hipMemsetAsync(cnt, 0, (size_t)n * 4, stream);

    int gm = (n + 31) / 32;
    k_matmul<<<gm, 256, 0, stream>>>(x, W, b, a, h2, u, v, n, ei, E, cnt);

    int B = (n + 255) / 256;
    k_scan_partial<<<B, 256, 0, stream>>>(cnt, psum, n);
    k_scan_final<<<B, 256, 0, stream>>>(cnt, psum, off, cur, n);

    // grid MUST be a multiple of 8 (8 virtual-XCD groups x 256 blocks)
    k_scatter<<<2048, 256, 0, stream>>>(ei, E, n, cur, edst);

    k_agg<<<(n + 3) / 4, 256, 0, stream>>>(edst, off, h2, u, v, ab, out, n);
}